// Round 1
// baseline (1300.217 us; speedup 1.0000x reference)
//
#include <hip/hip_runtime.h>

#define C_DIM 512
#define K_DIM 64
#define B_DIM 8
#define N_DIM 16384           // 128*128
#define BN_CNT (B_DIM * N_DIM)
#define BN_EPS 1e-5f
#define TILE_N 128
#define ES_STRIDE 132         // 128 + 4 pad: breaks power-of-2 LDS bank aliasing
#define K4_BLOCKS 256

// ---------------------------------------------------------------------------
// K1: tiny weight-folding GEMMs.
//   W0t[c][k] = sum_c' lin0_w[k][c'] * conv1_w[c'][c]   (transposed store: k fast)
//   W2p[o][k] = sum_c  conv2_w[o][c] * lin1_w[c][k]
//   b0[k]     = sum_c' lin0_w[k][c'] * conv1_b[c']
// ---------------------------------------------------------------------------
__global__ __launch_bounds__(256) void k_prep(
    const float* __restrict__ conv1_w, const float* __restrict__ conv1_b,
    const float* __restrict__ lin0_w, const float* __restrict__ lin1_w,
    const float* __restrict__ conv2_w,
    float* __restrict__ W0t, float* __restrict__ W2p, float* __restrict__ b0) {
  int id = blockIdx.x * 256 + threadIdx.x;
  if (id < C_DIM * K_DIM) {
    int c = id / K_DIM, k = id % K_DIM;
    float acc = 0.f;
    for (int cp = 0; cp < C_DIM; ++cp)
      acc = fmaf(lin0_w[k * C_DIM + cp], conv1_w[cp * C_DIM + c], acc);
    W0t[id] = acc;
  } else if (id < 2 * C_DIM * K_DIM) {
    int id2 = id - C_DIM * K_DIM;
    int o = id2 / K_DIM, k = id2 % K_DIM;
    float acc = 0.f;
    for (int cc = 0; cc < C_DIM; ++cc)
      acc = fmaf(conv2_w[o * C_DIM + cc], lin1_w[cc * K_DIM + k], acc);
    W2p[id2] = acc;
  } else if (id < 2 * C_DIM * K_DIM + K_DIM) {
    int k = id - 2 * C_DIM * K_DIM;
    float acc = 0.f;
    for (int cp = 0; cp < C_DIM; ++cp)
      acc = fmaf(lin0_w[k * C_DIM + cp], conv1_b[cp], acc);
    b0[k] = acc;
  }
}

// ---------------------------------------------------------------------------
// K2: A[b][k][n] = b0[k] + sum_c W0t[c][k] * x[b][c][n]
// One pixel per thread; acc[64] in VGPRs; W0t index is wave-uniform -> s_loads.
// ---------------------------------------------------------------------------
__global__ __launch_bounds__(256) void k_attn_logits(
    const float* __restrict__ x, const float* __restrict__ W0t,
    const float* __restrict__ b0, float* __restrict__ A) {
  int pix = blockIdx.x * 256 + threadIdx.x;
  int b = pix >> 14;
  int n = pix & 16383;
  const float* xp = x + (size_t)b * C_DIM * N_DIM + n;
  float acc[K_DIM];
#pragma unroll
  for (int k = 0; k < K_DIM; ++k) acc[k] = b0[k];
  for (int c = 0; c < C_DIM; ++c) {
    float xv = xp[(size_t)c * N_DIM];
    const float* w = W0t + c * K_DIM;
#pragma unroll
    for (int k = 0; k < K_DIM; ++k) acc[k] = fmaf(w[k], xv, acc[k]);
  }
  float* ap = A + (size_t)b * K_DIM * N_DIM + n;
#pragma unroll
  for (int k = 0; k < K_DIM; ++k) ap[(size_t)k * N_DIM] = acc[k];
}

// ---------------------------------------------------------------------------
// K3: per (b,k) row of 16384: rowmax and sum(exp(v - rowmax)) via online pass.
// ---------------------------------------------------------------------------
__global__ __launch_bounds__(256) void k_rowstats(
    const float* __restrict__ A, float* __restrict__ rowmax, float* __restrict__ rowsum) {
  int row = blockIdx.x;  // b*64 + k
  const float4* ap = (const float4*)(A + (size_t)row * N_DIM);
  float m = -1e30f, s = 0.f;
  for (int i = threadIdx.x; i < N_DIM / 4; i += 256) {
    float4 v = ap[i];
    float lm = fmaxf(fmaxf(v.x, v.y), fmaxf(v.z, v.w));
    float nm = fmaxf(m, lm);
    s = s * __expf(m - nm) + __expf(v.x - nm) + __expf(v.y - nm) +
        __expf(v.z - nm) + __expf(v.w - nm);
    m = nm;
  }
  __shared__ float sm[256], ss[256];
  sm[threadIdx.x] = m; ss[threadIdx.x] = s;
  __syncthreads();
  for (int off = 128; off >= 1; off >>= 1) {
    if (threadIdx.x < off) {
      float m1 = sm[threadIdx.x], s1 = ss[threadIdx.x];
      float m2 = sm[threadIdx.x + off], s2 = ss[threadIdx.x + off];
      float nm = fmaxf(m1, m2);
      sm[threadIdx.x] = nm;
      ss[threadIdx.x] = s1 * __expf(m1 - nm) + s2 * __expf(m2 - nm);
    }
    __syncthreads();
  }
  if (threadIdx.x == 0) { rowmax[row] = sm[0]; rowsum[row] = ss[0]; }
}

// ---------------------------------------------------------------------------
// K4: per (b, n-tile of 128): e = exp(A - rowmax)/rowsum; colsum over k;
// attn = e/(1e-9+colsum) written in-place to A; accumulate meanA and
// C = sum attn attn^T as per-block register partials.
// ---------------------------------------------------------------------------
__global__ __launch_bounds__(256) void k_softmax_renorm(
    float* __restrict__ A, const float* __restrict__ rowmax,
    const float* __restrict__ rowsum,
    float* __restrict__ meanApart, float* __restrict__ Cpart) {
  __shared__ float es[K_DIM][ES_STRIDE];
  __shared__ float csinv[TILE_N];
  __shared__ float rm[K_DIM], rsi[K_DIM];
  int t = threadIdx.x;
  float cacc[16];
#pragma unroll
  for (int i = 0; i < 16; ++i) cacc[i] = 0.f;
  float macc = 0.f;
  int k1 = t >> 2;
  int k2lo = t & 3;  // k2 = k2lo + 4*j  (j=0..15) -> conflict-free LDS banks

  int krow0 = t >> 5;        // 0..7
  int n4 = (t & 31) * 4;     // 0,4,...,124

  for (int tile = blockIdx.x; tile < B_DIM * (N_DIM / TILE_N); tile += gridDim.x) {
    int b = tile / (N_DIM / TILE_N);
    int n0 = (tile % (N_DIM / TILE_N)) * TILE_N;
    if (t < K_DIM) {
      rm[t] = rowmax[b * K_DIM + t];
      rsi[t] = 1.f / rowsum[b * K_DIM + t];
    }
    __syncthreads();
    float* ab = A + (size_t)b * K_DIM * N_DIM + n0;
#pragma unroll
    for (int kk = 0; kk < 8; ++kk) {
      int krow = kk * 8 + krow0;
      float4 v = *(const float4*)(ab + (size_t)krow * N_DIM + n4);
      float mm = rm[krow], si = rsi[krow];
      v.x = __expf(v.x - mm) * si;
      v.y = __expf(v.y - mm) * si;
      v.z = __expf(v.z - mm) * si;
      v.w = __expf(v.w - mm) * si;
      *(float4*)&es[krow][n4] = v;
    }
    __syncthreads();
    if (t < TILE_N) {
      float cs = 0.f;
#pragma unroll
      for (int k = 0; k < K_DIM; ++k) cs += es[k][t];
      csinv[t] = 1.f / (1e-9f + cs);
    }
    __syncthreads();
#pragma unroll
    for (int kk = 0; kk < 8; ++kk) {
      int krow = kk * 8 + krow0;
      float4 v = *(float4*)&es[krow][n4];
      float4 ci = *(const float4*)&csinv[n4];
      v.x *= ci.x; v.y *= ci.y; v.z *= ci.z; v.w *= ci.w;
      *(float4*)&es[krow][n4] = v;
      *(float4*)(ab + (size_t)krow * N_DIM + n4) = v;
    }
    __syncthreads();
    if (t < K_DIM) {
      float s = 0.f;
#pragma unroll 8
      for (int n = 0; n < TILE_N; ++n) s += es[t][n];
      macc += s;
    }
#pragma unroll 4
    for (int q = 0; q < TILE_N / 4; ++q) {
      float4 v1 = *(const float4*)&es[k1][q * 4];
#pragma unroll
      for (int j = 0; j < 16; ++j) {
        float4 v2 = *(const float4*)&es[k2lo + 4 * j][q * 4];
        cacc[j] = fmaf(v1.x, v2.x, cacc[j]);
        cacc[j] = fmaf(v1.y, v2.y, cacc[j]);
        cacc[j] = fmaf(v1.z, v2.z, cacc[j]);
        cacc[j] = fmaf(v1.w, v2.w, cacc[j]);
      }
    }
    __syncthreads();  // es reused next tile
  }
  if (t < K_DIM) meanApart[blockIdx.x * K_DIM + t] = macc;
  float* cp = Cpart + (size_t)blockIdx.x * (K_DIM * K_DIM) + k1 * K_DIM + k2lo;
#pragma unroll
  for (int j = 0; j < 16; ++j) cp[4 * j] = cacc[j];
}

// ---------------------------------------------------------------------------
// K5a: tree-reduce the per-block partials.
// ---------------------------------------------------------------------------
__global__ __launch_bounds__(256) void k_reduce_parts(
    const float* __restrict__ Cpart, const float* __restrict__ meanApart,
    float* __restrict__ Csum, float* __restrict__ meanA) {
  int j = blockIdx.x * 256 + threadIdx.x;
  if (j < K_DIM * K_DIM) {
    float s = 0.f;
    for (int p = 0; p < K4_BLOCKS; ++p) s += Cpart[(size_t)p * K_DIM * K_DIM + j];
    Csum[j] = s;
  } else if (j < K_DIM * K_DIM + K_DIM) {
    int k = j - K_DIM * K_DIM;
    float s = 0.f;
    for (int p = 0; p < K4_BLOCKS; ++p) s += meanApart[p * K_DIM + k];
    meanA[k] = s;
  }
}

// ---------------------------------------------------------------------------
// K5b: BN coefficients analytically:
//   mean[o] = (W2p[o]·meanA)/BN ; E[y²][o] = (W2p[o]·C·W2p[o]ᵀ)/BN
//   scale = gamma*rsqrt(var+eps); shift = beta - mean*scale
// ---------------------------------------------------------------------------
__global__ __launch_bounds__(64) void k_bn_coeffs(
    const float* __restrict__ W2p, const float* __restrict__ Csum,
    const float* __restrict__ meanA,
    const float* __restrict__ gamma, const float* __restrict__ beta,
    float* __restrict__ scale, float* __restrict__ shift) {
  __shared__ float Cs[K_DIM][K_DIM];
  __shared__ float mAs[K_DIM];
  int t = threadIdx.x;
  for (int i = t; i < K_DIM * K_DIM; i += 64) ((float*)Cs)[i] = Csum[i];
  mAs[t] = meanA[t];
  __syncthreads();
  int o = blockIdx.x * 64 + t;
  float w[K_DIM];
#pragma unroll
  for (int k = 0; k < K_DIM; ++k) w[k] = W2p[o * K_DIM + k];
  const float invBN = 1.f / (float)BN_CNT;
  float m = 0.f;
#pragma unroll
  for (int k = 0; k < K_DIM; ++k) m = fmaf(w[k], mAs[k], m);
  m *= invBN;
  float q = 0.f;
  for (int k = 0; k < K_DIM; ++k) {
    float tk = 0.f;
#pragma unroll
    for (int kp = 0; kp < K_DIM; ++kp) tk = fmaf(w[kp], Cs[kp][k], tk);
    q = fmaf(tk, w[k], q);
  }
  q *= invBN;
  float var = q - m * m;
  float sc = gamma[o] * rsqrtf(var + BN_EPS);
  scale[o] = sc;
  shift[o] = beta[o] - m * sc;
}

// ---------------------------------------------------------------------------
// K6: out[b][o][n] = relu(scale[o]*(W2p[o]·attn[b][:][n]) + shift[o] + x[b][o][n])
// One pixel per thread; attn[64] in VGPRs; W2p/scale/shift wave-uniform -> s_loads.
// ---------------------------------------------------------------------------
__global__ __launch_bounds__(256) void k_output(
    const float* __restrict__ x, const float* __restrict__ A,
    const float* __restrict__ W2p, const float* __restrict__ scale,
    const float* __restrict__ shift, float* __restrict__ out) {
  int pix = blockIdx.x * 256 + threadIdx.x;
  int b = pix >> 14;
  int n = pix & 16383;
  const float* ap = A + (size_t)b * K_DIM * N_DIM + n;
  float at[K_DIM];
#pragma unroll
  for (int k = 0; k < K_DIM; ++k) at[k] = ap[(size_t)k * N_DIM];
  const float* xp = x + (size_t)b * C_DIM * N_DIM + n;
  float* op = out + (size_t)b * C_DIM * N_DIM + n;
  for (int o = 0; o < C_DIM; ++o) {
    const float* w = W2p + o * K_DIM;
    float xv = xp[(size_t)o * N_DIM];
    float a0 = 0.f, a1 = 0.f, a2 = 0.f, a3 = 0.f;
#pragma unroll
    for (int k = 0; k < K_DIM; k += 4) {
      a0 = fmaf(w[k], at[k], a0);
      a1 = fmaf(w[k + 1], at[k + 1], a1);
      a2 = fmaf(w[k + 2], at[k + 2], a2);
      a3 = fmaf(w[k + 3], at[k + 3], a3);
    }
    float y = (a0 + a1) + (a2 + a3);
    y = fmaf(y, scale[o], shift[o]) + xv;
    op[(size_t)o * N_DIM] = fmaxf(y, 0.f);
  }
}

extern "C" void kernel_launch(void* const* d_in, const int* in_sizes, int n_in,
                              void* d_out, int out_size, void* d_ws, size_t ws_size,
                              hipStream_t stream) {
  (void)in_sizes; (void)n_in; (void)out_size; (void)ws_size;
  const float* x       = (const float*)d_in[0];
  const float* conv1_w = (const float*)d_in[1];
  const float* conv1_b = (const float*)d_in[2];
  const float* lin0_w  = (const float*)d_in[3];
  const float* lin1_w  = (const float*)d_in[4];
  const float* conv2_w = (const float*)d_in[5];
  const float* gamma   = (const float*)d_in[6];
  const float* beta    = (const float*)d_in[7];
  float* out = (float*)d_out;
  float* ws  = (float*)d_ws;

  float* A         = ws;                                       // 8*64*16384
  float* W0t       = A + (size_t)B_DIM * K_DIM * N_DIM;        // 512*64
  float* W2p       = W0t + C_DIM * K_DIM;                      // 512*64
  float* b0        = W2p + C_DIM * K_DIM;                      // 64
  float* rowmax    = b0 + K_DIM;                               // 512
  float* rowsum    = rowmax + B_DIM * K_DIM;                   // 512
  float* meanApart = rowsum + B_DIM * K_DIM;                   // 256*64
  float* Cpart     = meanApart + K4_BLOCKS * K_DIM;            // 256*4096
  float* meanA     = Cpart + (size_t)K4_BLOCKS * K_DIM * K_DIM;// 64
  float* Csum      = meanA + K_DIM;                            // 4096
  float* scale     = Csum + K_DIM * K_DIM;                     // 512
  float* shift     = scale + C_DIM;                            // 512

  k_prep<<<(2 * C_DIM * K_DIM + K_DIM + 255) / 256, 256, 0, stream>>>(
      conv1_w, conv1_b, lin0_w, lin1_w, conv2_w, W0t, W2p, b0);
  k_attn_logits<<<(B_DIM * N_DIM) / 256, 256, 0, stream>>>(x, W0t, b0, A);
  k_rowstats<<<B_DIM * K_DIM, 256, 0, stream>>>(A, rowmax, rowsum);
  k_softmax_renorm<<<K4_BLOCKS, 256, 0, stream>>>(A, rowmax, rowsum, meanApart, Cpart);
  k_reduce_parts<<<(K_DIM * K_DIM + K_DIM + 255) / 256, 256, 0, stream>>>(
      Cpart, meanApart, Csum, meanA);
  k_bn_coeffs<<<C_DIM / 64, 64, 0, stream>>>(W2p, Csum, meanA, gamma, beta, scale, shift);
  k_output<<<(B_DIM * N_DIM) / 256, 256, 0, stream>>>(x, A, W2p, scale, shift, out);
}

// Round 2
// 1058.388 us; speedup vs baseline: 1.2285x; 1.2285x over previous
//
#include <hip/hip_runtime.h>

#define C_DIM 512
#define K_DIM 64
#define B_DIM 8
#define N_DIM 16384           // 128*128
#define BN_CNT (B_DIM * N_DIM)
#define BN_EPS 1e-5f
#define TILE_N 128
#define ES_STRIDE 132         // 128 + 4 pad: breaks power-of-2 LDS bank aliasing
#define OCHUNK 128            // k_output o-chunk: grid x4 for occupancy
#define K4_MAX 512

// ---------------------------------------------------------------------------
// K1: tiny weight-folding GEMMs.
//   W0t[c][k] = sum_c' lin0_w[k][c'] * conv1_w[c'][c]   (k fast in store)
//   W2p[o][k] = sum_c  conv2_w[o][c] * lin1_w[c][k]
//   b0[k]     = sum_c' lin0_w[k][c'] * conv1_b[c']
// Lane mapping chosen so the k-indexed weight is wave-uniform (s_load) and
// the other operand is lane-coalesced.
// ---------------------------------------------------------------------------
__global__ __launch_bounds__(256) void k_prep(
    const float* __restrict__ conv1_w, const float* __restrict__ conv1_b,
    const float* __restrict__ lin0_w, const float* __restrict__ lin1_w,
    const float* __restrict__ conv2_w,
    float* __restrict__ W0t, float* __restrict__ W2p, float* __restrict__ b0) {
  int id = blockIdx.x * 256 + threadIdx.x;
  if (id < C_DIM * K_DIM) {
    int k = id >> 9;         // lanes span c -> conv1_w coalesced, lin0_w uniform
    int c = id & 511;
    float acc = 0.f;
#pragma unroll 4
    for (int cp = 0; cp < C_DIM; ++cp)
      acc = fmaf(lin0_w[k * C_DIM + cp], conv1_w[cp * C_DIM + c], acc);
    W0t[c * K_DIM + k] = acc;
  } else if (id < 2 * C_DIM * K_DIM) {
    int id2 = id - C_DIM * K_DIM;
    int o = id2 >> 6, k = id2 & 63;  // lanes span k -> lin1_w coalesced, conv2_w uniform
    float acc = 0.f;
#pragma unroll 4
    for (int cc = 0; cc < C_DIM; ++cc)
      acc = fmaf(conv2_w[o * C_DIM + cc], lin1_w[cc * K_DIM + k], acc);
    W2p[id2] = acc;
  } else if (id < 2 * C_DIM * K_DIM + K_DIM) {
    int k = id - 2 * C_DIM * K_DIM;
    float acc = 0.f;
    for (int cp = 0; cp < C_DIM; ++cp)
      acc = fmaf(lin0_w[k * C_DIM + cp], conv1_b[cp], acc);
    b0[k] = acc;
  }
}

// ---------------------------------------------------------------------------
// K2: A[b][k][n] = b0[k] + sum_c W0t[c][k] * x[b][c][n]
// One pixel/thread; acc[64] in VGPRs. c-loop unrolled x8 with batched loads:
// 8 outstanding 256B loads/wave -> HBM latency hidden at 2 blocks/CU.
// ---------------------------------------------------------------------------
__global__ __launch_bounds__(256) void k_attn_logits(
    const float* __restrict__ x, const float* __restrict__ W0t,
    const float* __restrict__ b0, float* __restrict__ A) {
  int pix = blockIdx.x * 256 + threadIdx.x;
  int b = pix >> 14;
  int n = pix & 16383;
  const float* xp = x + (size_t)b * C_DIM * N_DIM + n;
  float acc[K_DIM];
#pragma unroll
  for (int k = 0; k < K_DIM; ++k) acc[k] = b0[k];
  for (int c = 0; c < C_DIM; c += 8) {
    float xv[8];
#pragma unroll
    for (int j = 0; j < 8; ++j) xv[j] = xp[(size_t)(c + j) * N_DIM];
#pragma unroll
    for (int j = 0; j < 8; ++j) {
      const float* w = W0t + (c + j) * K_DIM;
#pragma unroll
      for (int k = 0; k < K_DIM; ++k) acc[k] = fmaf(w[k], xv[j], acc[k]);
    }
  }
  float* ap = A + (size_t)b * K_DIM * N_DIM + n;
#pragma unroll
  for (int k = 0; k < K_DIM; ++k) ap[(size_t)k * N_DIM] = acc[k];
}

// ---------------------------------------------------------------------------
// K3: per (b,k) row of 16384: rowmax and sum(exp(v - rowmax)), online.
// ---------------------------------------------------------------------------
__global__ __launch_bounds__(256) void k_rowstats(
    const float* __restrict__ A, float* __restrict__ rowmax, float* __restrict__ rowsum) {
  int row = blockIdx.x;  // b*64 + k
  const float4* ap = (const float4*)(A + (size_t)row * N_DIM);
  float m = -1e30f, s = 0.f;
  for (int i = threadIdx.x; i < N_DIM / 4; i += 256) {
    float4 v = ap[i];
    float lm = fmaxf(fmaxf(v.x, v.y), fmaxf(v.z, v.w));
    float nm = fmaxf(m, lm);
    s = s * __expf(m - nm) + __expf(v.x - nm) + __expf(v.y - nm) +
        __expf(v.z - nm) + __expf(v.w - nm);
    m = nm;
  }
  __shared__ float sm[256], ss[256];
  sm[threadIdx.x] = m; ss[threadIdx.x] = s;
  __syncthreads();
  for (int off = 128; off >= 1; off >>= 1) {
    if (threadIdx.x < off) {
      float m1 = sm[threadIdx.x], s1 = ss[threadIdx.x];
      float m2 = sm[threadIdx.x + off], s2 = ss[threadIdx.x + off];
      float nm = fmaxf(m1, m2);
      sm[threadIdx.x] = nm;
      ss[threadIdx.x] = s1 * __expf(m1 - nm) + s2 * __expf(m2 - nm);
    }
    __syncthreads();
  }
  if (threadIdx.x == 0) { rowmax[row] = sm[0]; rowsum[row] = ss[0]; }
}

// ---------------------------------------------------------------------------
// K4: per (b, n-tile of 128): e = exp(A - rowmax)/rowsum; colsum over k;
// attn = e/(1e-9+colsum) in-place to A; accumulate meanA and C = attn attn^T
// as per-block register partials. Grid-stride over 1024 tiles.
// ---------------------------------------------------------------------------
__global__ __launch_bounds__(256) void k_softmax_renorm(
    float* __restrict__ A, const float* __restrict__ rowmax,
    const float* __restrict__ rowsum,
    float* __restrict__ meanApart, float* __restrict__ Cpart) {
  __shared__ float es[K_DIM][ES_STRIDE];
  __shared__ float csinv[TILE_N];
  __shared__ float rm[K_DIM], rsi[K_DIM];
  int t = threadIdx.x;
  float cacc[16];
#pragma unroll
  for (int i = 0; i < 16; ++i) cacc[i] = 0.f;
  float macc = 0.f;
  int k1 = t >> 2;
  int k2lo = t & 3;  // k2 = k2lo + 4*j -> conflict-free LDS banks

  int krow0 = t >> 5;        // 0..7
  int n4 = (t & 31) * 4;     // 0,4,...,124

  for (int tile = blockIdx.x; tile < B_DIM * (N_DIM / TILE_N); tile += gridDim.x) {
    int b = tile / (N_DIM / TILE_N);
    int n0 = (tile % (N_DIM / TILE_N)) * TILE_N;
    if (t < K_DIM) {
      rm[t] = rowmax[b * K_DIM + t];
      rsi[t] = 1.f / rowsum[b * K_DIM + t];
    }
    __syncthreads();
    float* ab = A + (size_t)b * K_DIM * N_DIM + n0;
#pragma unroll
    for (int kk = 0; kk < 8; ++kk) {
      int krow = kk * 8 + krow0;
      float4 v = *(const float4*)(ab + (size_t)krow * N_DIM + n4);
      float mm = rm[krow], si = rsi[krow];
      v.x = __expf(v.x - mm) * si;
      v.y = __expf(v.y - mm) * si;
      v.z = __expf(v.z - mm) * si;
      v.w = __expf(v.w - mm) * si;
      *(float4*)&es[krow][n4] = v;
    }
    __syncthreads();
    if (t < TILE_N) {
      float cs = 0.f;
#pragma unroll
      for (int k = 0; k < K_DIM; ++k) cs += es[k][t];
      csinv[t] = 1.f / (1e-9f + cs);
    }
    __syncthreads();
#pragma unroll
    for (int kk = 0; kk < 8; ++kk) {
      int krow = kk * 8 + krow0;
      float4 v = *(float4*)&es[krow][n4];
      float4 ci = *(const float4*)&csinv[n4];
      v.x *= ci.x; v.y *= ci.y; v.z *= ci.z; v.w *= ci.w;
      *(float4*)&es[krow][n4] = v;
      *(float4*)(ab + (size_t)krow * N_DIM + n4) = v;
    }
    __syncthreads();
    if (t < K_DIM) {
      float s = 0.f;
#pragma unroll 8
      for (int n = 0; n < TILE_N; ++n) s += es[t][n];
      macc += s;
    }
#pragma unroll 4
    for (int q = 0; q < TILE_N / 4; ++q) {
      float4 v1 = *(const float4*)&es[k1][q * 4];
#pragma unroll
      for (int j = 0; j < 16; ++j) {
        float4 v2 = *(const float4*)&es[k2lo + 4 * j][q * 4];
        cacc[j] = fmaf(v1.x, v2.x, cacc[j]);
        cacc[j] = fmaf(v1.y, v2.y, cacc[j]);
        cacc[j] = fmaf(v1.z, v2.z, cacc[j]);
        cacc[j] = fmaf(v1.w, v2.w, cacc[j]);
      }
    }
    __syncthreads();  // es reused next tile
  }
  if (t < K_DIM) meanApart[blockIdx.x * K_DIM + t] = macc;
  float* cp = Cpart + (size_t)blockIdx.x * (K_DIM * K_DIM) + k1 * K_DIM + k2lo;
#pragma unroll
  for (int j = 0; j < 16; ++j) cp[4 * j] = cacc[j];
}

// ---------------------------------------------------------------------------
// K5a: tree-reduce the per-block partials (P = runtime block count of K4).
// ---------------------------------------------------------------------------
__global__ __launch_bounds__(256) void k_reduce_parts(
    const float* __restrict__ Cpart, const float* __restrict__ meanApart,
    float* __restrict__ Csum, float* __restrict__ meanA, int P) {
  int j = blockIdx.x * 256 + threadIdx.x;
  if (j < K_DIM * K_DIM) {
    float s = 0.f;
    for (int p = 0; p < P; ++p) s += Cpart[(size_t)p * K_DIM * K_DIM + j];
    Csum[j] = s;
  } else if (j < K_DIM * K_DIM + K_DIM) {
    int k = j - K_DIM * K_DIM;
    float s = 0.f;
    for (int p = 0; p < P; ++p) s += meanApart[p * K_DIM + k];
    meanA[k] = s;
  }
}

// ---------------------------------------------------------------------------
// K5b: BN coefficients analytically:
//   mean[o] = (W2p[o]·meanA)/BN ; E[y²][o] = (W2p[o]·C·W2p[o]ᵀ)/BN
// ---------------------------------------------------------------------------
__global__ __launch_bounds__(64) void k_bn_coeffs(
    const float* __restrict__ W2p, const float* __restrict__ Csum,
    const float* __restrict__ meanA,
    const float* __restrict__ gamma, const float* __restrict__ beta,
    float* __restrict__ scale, float* __restrict__ shift) {
  __shared__ float Cs[K_DIM][K_DIM];
  __shared__ float mAs[K_DIM];
  int t = threadIdx.x;
  for (int i = t; i < K_DIM * K_DIM; i += 64) ((float*)Cs)[i] = Csum[i];
  mAs[t] = meanA[t];
  __syncthreads();
  int o = blockIdx.x * 64 + t;
  float w[K_DIM];
#pragma unroll
  for (int k = 0; k < K_DIM; ++k) w[k] = W2p[o * K_DIM + k];
  const float invBN = 1.f / (float)BN_CNT;
  float m = 0.f;
#pragma unroll
  for (int k = 0; k < K_DIM; ++k) m = fmaf(w[k], mAs[k], m);
  m *= invBN;
  float q = 0.f;
  for (int k = 0; k < K_DIM; ++k) {
    float tk = 0.f;
#pragma unroll
    for (int kp = 0; kp < K_DIM; ++kp) tk = fmaf(w[kp], Cs[kp][k], tk);
    q = fmaf(tk, w[k], q);
  }
  q *= invBN;
  float var = q - m * m;
  float sc = gamma[o] * rsqrtf(var + BN_EPS);
  scale[o] = sc;
  shift[o] = beta[o] - m * sc;
}

// ---------------------------------------------------------------------------
// K6: out[b][o][n] = relu(scale[o]*(W2p[o]·attn[b][:][n]) + shift[o] + x[b][o][n])
// blockIdx.y selects a 128-wide o-chunk (grid x4 -> 16 waves/CU); o-loop
// unrolled x8 with batched loads for 8 outstanding loads/wave.
// ---------------------------------------------------------------------------
__global__ __launch_bounds__(256) void k_output(
    const float* __restrict__ x, const float* __restrict__ A,
    const float* __restrict__ W2p, const float* __restrict__ scale,
    const float* __restrict__ shift, float* __restrict__ out) {
  int pix = blockIdx.x * 256 + threadIdx.x;
  int b = pix >> 14;
  int n = pix & 16383;
  int o0 = blockIdx.y * OCHUNK;
  const float* ap = A + (size_t)b * K_DIM * N_DIM + n;
  float at[K_DIM];
#pragma unroll
  for (int k = 0; k < K_DIM; ++k) at[k] = ap[(size_t)k * N_DIM];
  const float* xp = x + (size_t)b * C_DIM * N_DIM + n;
  float* op = out + (size_t)b * C_DIM * N_DIM + n;
  for (int o = o0; o < o0 + OCHUNK; o += 8) {
    float xv[8];
#pragma unroll
    for (int j = 0; j < 8; ++j) xv[j] = xp[(size_t)(o + j) * N_DIM];
    float y[8];
#pragma unroll
    for (int j = 0; j < 8; ++j) {
      const float* w = W2p + (o + j) * K_DIM;
      float a0 = 0.f, a1 = 0.f, a2 = 0.f, a3 = 0.f;
#pragma unroll
      for (int k = 0; k < K_DIM; k += 4) {
        a0 = fmaf(w[k], at[k], a0);
        a1 = fmaf(w[k + 1], at[k + 1], a1);
        a2 = fmaf(w[k + 2], at[k + 2], a2);
        a3 = fmaf(w[k + 3], at[k + 3], a3);
      }
      float yy = (a0 + a1) + (a2 + a3);
      y[j] = fmaf(yy, scale[o + j], shift[o + j]) + xv[j];
    }
#pragma unroll
    for (int j = 0; j < 8; ++j)
      op[(size_t)(o + j) * N_DIM] = fmaxf(y[j], 0.f);
  }
}

extern "C" void kernel_launch(void* const* d_in, const int* in_sizes, int n_in,
                              void* d_out, int out_size, void* d_ws, size_t ws_size,
                              hipStream_t stream) {
  (void)in_sizes; (void)n_in; (void)out_size;
  const float* x       = (const float*)d_in[0];
  const float* conv1_w = (const float*)d_in[1];
  const float* conv1_b = (const float*)d_in[2];
  const float* lin0_w  = (const float*)d_in[3];
  const float* lin1_w  = (const float*)d_in[4];
  const float* conv2_w = (const float*)d_in[5];
  const float* gamma   = (const float*)d_in[6];
  const float* beta    = (const float*)d_in[7];
  float* out = (float*)d_out;
  float* ws  = (float*)d_ws;

  float* A      = ws;                                        // 8*64*16384
  float* W0t    = A + (size_t)B_DIM * K_DIM * N_DIM;         // 512*64
  float* W2p    = W0t + C_DIM * K_DIM;                       // 512*64
  float* b0     = W2p + C_DIM * K_DIM;                       // 64
  float* rowmax = b0 + K_DIM;                                // 512
  float* rowsum = rowmax + B_DIM * K_DIM;                    // 512
  float* meanA  = rowsum + B_DIM * K_DIM;                    // 64
  float* Csum   = meanA + K_DIM;                             // 4096
  float* scale  = Csum + K_DIM * K_DIM;                      // 512
  float* shift  = scale + C_DIM;                             // 512
  float* meanApart = shift + C_DIM;                          // P*64
  // Cpart sized by remaining ws: pick K4 block count P at runtime.
  size_t used = (size_t)(meanApart - ws);
  size_t avail = ws_size / sizeof(float) - used;
  int P = (int)(avail / (K_DIM * K_DIM + K_DIM));
  if (P > K4_MAX) P = K4_MAX;
  if (P > 256) P = 512 <= P ? 512 : 256;  // prefer 512 else 256 for clean strides
  if (P < 1) P = 1;
  float* Cpart = meanApart + (size_t)P * K_DIM;

  k_prep<<<(2 * C_DIM * K_DIM + K_DIM + 255) / 256, 256, 0, stream>>>(
      conv1_w, conv1_b, lin0_w, lin1_w, conv2_w, W0t, W2p, b0);
  k_attn_logits<<<(B_DIM * N_DIM) / 256, 256, 0, stream>>>(x, W0t, b0, A);
  k_rowstats<<<B_DIM * K_DIM, 256, 0, stream>>>(A, rowmax, rowsum);
  k_softmax_renorm<<<P, 256, 0, stream>>>(A, rowmax, rowsum, meanApart, Cpart);
  k_reduce_parts<<<(K_DIM * K_DIM + K_DIM + 255) / 256, 256, 0, stream>>>(
      Cpart, meanApart, Csum, meanA, P);
  k_bn_coeffs<<<C_DIM / 64, 64, 0, stream>>>(W2p, Csum, meanA, gamma, beta, scale, shift);
  dim3 og((B_DIM * N_DIM) / 256, C_DIM / OCHUNK);
  k_output<<<og, 256, 0, stream>>>(x, A, W2p, scale, shift, out);
}